// Round 1
// baseline (176.522 us; speedup 1.0000x reference)
//
#include <hip/hip_runtime.h>

// EfficientAdditiveAttention  B=8, L=512, D=128
//
// combined(q,k) = sum_d w_all[d]*tanh(Q[q,d]+K[k,d]) (+ const)   -> softmax_k -> @V
// tanh(z) = 1 - 2/(1+exp(2z)); the "1" term and all constant biases are
// softmax-invariant and dropped. Q,K are pre-scaled by 2*log2(e) at projection
// time so the hot loop is: v_add, v_exp, v_add, v_rcp, v_fma per (k,d) element.

#define BB 8
#define LL 512
#define DD 128
#define NROW (BB*LL)            // 4096 rows
#define MATN (NROW*DD)          // 524288 elements per matrix

static constexpr float C1 = 2.8853900817779268f;   // 2*log2(e)  (pre-scale for Q,K)
static constexpr float C2 = -2.8853900817779268f;  // -2*log2(e) (softmax exp fold)
static constexpr float INV_SCALE = 0.08838834764831845f; // 1/sqrt(128)

__device__ __forceinline__ float fast_exp2(float x) {
#if __has_builtin(__builtin_amdgcn_exp2f)
    return __builtin_amdgcn_exp2f(x);
#else
    return exp2f(x);
#endif
}
__device__ __forceinline__ float fast_rcp(float x) {
#if __has_builtin(__builtin_amdgcn_rcpf)
    return __builtin_amdgcn_rcpf(x);
#else
    return 1.0f / x;
#endif
}

// ---------------------------------------------------------------------------
// Projection: out = X @ W.T + b, scaled by C1 for Q,K. 3 matrices x 64 row-tiles.
// Block: 256 threads, 64 rows x 128 cols tile, K split into 2 halves of 64.
// Thread computes 8 rows x 4 cols (cols strided by 32 so b-frag LDS reads are
// conflict-free). LDS rows padded to 66 floats (float2-aligned, balanced banks).
// ---------------------------------------------------------------------------
__global__ __launch_bounds__(256) void proj_kernel(
    const float* __restrict__ query, const float* __restrict__ key,
    const float* __restrict__ value,
    const float* __restrict__ Wq, const float* __restrict__ bq,
    const float* __restrict__ Wk, const float* __restrict__ bk,
    const float* __restrict__ Wv, const float* __restrict__ bv,
    const float* __restrict__ wd, const float* __restrict__ wsg,
    const float* __restrict__ wt, float* __restrict__ ws)
{
    __shared__ float Wl[128 * 66];   // 33792 B
    __shared__ float Xl[64 * 66];    // 16896 B

    const int bx = blockIdx.x;
    const int m  = bx >> 6;          // 0:Q 1:K 2:V
    const int r0 = (bx & 63) * 64;
    const float* X    = (m == 0) ? query : (m == 1) ? key : value;
    const float* W    = (m == 0) ? Wq    : (m == 1) ? Wk  : Wv;
    const float* bias = (m == 0) ? bq    : (m == 1) ? bk  : bv;
    float* outp = ws + (size_t)m * MATN;
    const float scale = (m == 2) ? 1.0f : C1;
    const int t = threadIdx.x;

    // w_all -> ws tail (done once by block 0; softmax-invariant bias dropped)
    if (bx == 0 && t < 128) {
        ws[(size_t)3 * MATN + t] = INV_SCALE + wd[t] + wsg[t] + wt[t];
    }

    const int cg = t & 31;   // cols: cg + 32*j
    const int rg = t >> 5;   // rows: rg*8 + i

    float acc[8][4];
    #pragma unroll
    for (int j = 0; j < 4; ++j) {
        float bj = bias[cg + 32 * j];
        #pragma unroll
        for (int i = 0; i < 8; ++i) acc[i][j] = bj;
    }

    const float4* Wsrc = (const float4*)W;

    for (int h = 0; h < 2; ++h) {            // K-dim halves (d = h*64 .. +63)
        __syncthreads();
        // stage W half: 128 rows x 16 float4
        #pragma unroll
        for (int j = 0; j < 8; ++j) {
            int g = t + j * 256;             // 0..2047
            int c = g >> 4, f4 = g & 15;
            float4 v = Wsrc[c * 32 + h * 16 + f4];
            float* dst = &Wl[c * 66 + f4 * 4];
            *(float2*)dst       = make_float2(v.x, v.y);
            *(float2*)(dst + 2) = make_float2(v.z, v.w);
        }
        // stage X half: 64 rows x 16 float4
        const float4* Xsrc = (const float4*)(X + (size_t)r0 * DD);
        #pragma unroll
        for (int j = 0; j < 4; ++j) {
            int g = t + j * 256;             // 0..1023
            int r = g >> 4, f4 = g & 15;
            float4 v = Xsrc[r * 32 + h * 16 + f4];
            float* dst = &Xl[r * 66 + f4 * 4];
            *(float2*)dst       = make_float2(v.x, v.y);
            *(float2*)(dst + 2) = make_float2(v.z, v.w);
        }
        __syncthreads();

        #pragma unroll 8
        for (int dg = 0; dg < 32; ++dg) {    // float2 granules over this half
            float2 bf[4];
            #pragma unroll
            for (int j = 0; j < 4; ++j)
                bf[j] = *(const float2*)&Wl[(cg + 32 * j) * 66 + 2 * dg];
            float2 af[8];
            #pragma unroll
            for (int i = 0; i < 8; ++i)
                af[i] = *(const float2*)&Xl[(rg * 8 + i) * 66 + 2 * dg];
            #pragma unroll
            for (int i = 0; i < 8; ++i)
                #pragma unroll
                for (int j = 0; j < 4; ++j)
                    acc[i][j] += af[i].x * bf[j].x + af[i].y * bf[j].y;
        }
    }

    #pragma unroll
    for (int i = 0; i < 8; ++i) {
        int r = r0 + rg * 8 + i;
        #pragma unroll
        for (int j = 0; j < 4; ++j)
            outp[(size_t)r * DD + cg + 32 * j] = acc[i][j] * scale;
    }
}

// ---------------------------------------------------------------------------
// Main attention kernel.
// Grid: 512 blocks x 512 threads (8 waves). Block owns 8 consecutive q rows
// (one per wave), all within one batch b. Pass A: lane owns one k per 64-k
// tile, loops d=0..127 with K-tile in LDS (row stride 130), Q-row + w_all via
// wave-uniform (scalar) loads. Pass B: lane owns d={2*lane,2*lane+1}, V tiles
// staged into the same LDS buffer, p broadcast from LDS.
// ---------------------------------------------------------------------------
__global__ __launch_bounds__(512) void attn_kernel(
    const float* __restrict__ ws, float* __restrict__ out)
{
    __shared__ float KV[64 * 130];   // 33280 B (K tile, then reused for V)
    __shared__ float P[8 * 512];     // 16384 B  (p per wave per k)

    const float* Qp   = ws;
    const float* Kp   = ws + (size_t)MATN;
    const float* Vp   = ws + (size_t)2 * MATN;
    const float* Wall = ws + (size_t)3 * MATN;

    const int bx   = blockIdx.x;
    const int b    = bx >> 6;                 // 64 blocks per batch
    const int q0   = bx * 8;
    const int wave = __builtin_amdgcn_readfirstlane((int)threadIdx.x >> 6);
    const int lane = threadIdx.x & 63;
    const int q    = q0 + wave;               // global q row, wave-uniform

    const float* __restrict__ Qrow = Qp + (size_t)q * DD;   // uniform -> s_load
    const float* __restrict__ Kb   = Kp + (size_t)b * (LL * DD);
    const float* __restrict__ Vb   = Vp + (size_t)b * (LL * DD);

    // ---------------- Pass A: logits + exp ----------------
    float psum = 0.f;
    const float* krow = &KV[lane * 130];

    for (int tt = 0; tt < 8; ++tt) {
        __syncthreads();
        {   // stage K tile rows tt*64 .. +63 (8192 floats, 4 float4/thread)
            const float4* src = (const float4*)(Kb + (size_t)tt * 64 * DD);
            #pragma unroll
            for (int j = 0; j < 4; ++j) {
                int g = threadIdx.x + j * 512;     // 0..2047
                int row = g >> 5, c4 = g & 31;
                float4 v = src[g];
                float* dst = &KV[row * 130 + c4 * 4];
                *(float2*)dst       = make_float2(v.x, v.y);
                *(float2*)(dst + 2) = make_float2(v.z, v.w);
            }
        }
        __syncthreads();

        float s0 = 0.f, s1 = 0.f, s2 = 0.f, s3 = 0.f;
        #pragma unroll 4
        for (int d = 0; d < DD; d += 4) {
            float4 qv  = *(const float4*)(Qrow + d);    // wave-uniform
            float4 wv  = *(const float4*)(Wall + d);    // wave-uniform
            float2 k01 = *(const float2*)(krow + d);
            float2 k23 = *(const float2*)(krow + d + 2);
            s0 += wv.x * fast_rcp(1.0f + fast_exp2(qv.x + k01.x));
            s1 += wv.y * fast_rcp(1.0f + fast_exp2(qv.y + k01.y));
            s2 += wv.z * fast_rcp(1.0f + fast_exp2(qv.z + k23.x));
            s3 += wv.w * fast_rcp(1.0f + fast_exp2(qv.w + k23.y));
        }
        float p = fast_exp2(C2 * ((s0 + s1) + (s2 + s3)));
        P[wave * 512 + tt * 64 + lane] = p;
        psum += p;
    }

    // wave-wide sum of p (no softmax-max needed: |logit| bounded ~15)
    #pragma unroll
    for (int off = 32; off; off >>= 1) psum += __shfl_xor(psum, off);

    // ---------------- Pass B: out = (p @ V) / sum ----------------
    float o0 = 0.f, o1 = 0.f;
    const int d2 = 2 * lane;

    for (int tt = 0; tt < 8; ++tt) {
        __syncthreads();
        {   // stage V tile into same buffer
            const float4* src = (const float4*)(Vb + (size_t)tt * 64 * DD);
            #pragma unroll
            for (int j = 0; j < 4; ++j) {
                int g = threadIdx.x + j * 512;
                int row = g >> 5, c4 = g & 31;
                float4 v = src[g];
                float* dst = &KV[row * 130 + c4 * 4];
                *(float2*)dst       = make_float2(v.x, v.y);
                *(float2*)(dst + 2) = make_float2(v.z, v.w);
            }
        }
        __syncthreads();

        const float* prow = &P[wave * 512 + tt * 64];
        #pragma unroll 4
        for (int j = 0; j < 64; j += 4) {
            float4 pv = *(const float4*)(prow + j);     // LDS broadcast
            float2 v0 = *(const float2*)&KV[(j + 0) * 130 + d2];
            float2 v1 = *(const float2*)&KV[(j + 1) * 130 + d2];
            float2 v2 = *(const float2*)&KV[(j + 2) * 130 + d2];
            float2 v3 = *(const float2*)&KV[(j + 3) * 130 + d2];
            o0 += pv.x * v0.x + pv.y * v1.x + pv.z * v2.x + pv.w * v3.x;
            o1 += pv.x * v0.y + pv.y * v1.y + pv.z * v2.y + pv.w * v3.y;
        }
    }

    float inv = fast_rcp(psum);
    *(float2*)&out[(size_t)q * DD + d2] = make_float2(o0 * inv, o1 * inv);
}

// ---------------------------------------------------------------------------
extern "C" void kernel_launch(void* const* d_in, const int* in_sizes, int n_in,
                              void* d_out, int out_size, void* d_ws, size_t ws_size,
                              hipStream_t stream) {
    const float* query = (const float*)d_in[0];
    const float* key_  = (const float*)d_in[1];
    const float* value = (const float*)d_in[2];
    const float* Wq    = (const float*)d_in[3];
    const float* bq    = (const float*)d_in[4];
    const float* Wk    = (const float*)d_in[5];
    const float* bk    = (const float*)d_in[6];
    const float* Wv    = (const float*)d_in[7];
    const float* bv    = (const float*)d_in[8];
    const float* wd    = (const float*)d_in[9];
    // d_in[10] b_delta, d_in[12] b_sigma, d_in[14] b_theta: softmax-invariant, dropped
    const float* wsg   = (const float*)d_in[11];
    const float* wt    = (const float*)d_in[13];
    float* ws = (float*)d_ws;   // needs (3*524288 + 128)*4 ~= 6 MB

    proj_kernel<<<192, 256, 0, stream>>>(query, key_, value,
                                         Wq, bq, Wk, bk, Wv, bv,
                                         wd, wsg, wt, ws);
    attn_kernel<<<512, 512, 0, stream>>>(ws, (float*)d_out);
}